// Round 10
// baseline (105.180 us; speedup 1.0000x reference)
//
#include <hip/hip_runtime.h>
#include <math.h>

typedef _Float16 f16;
typedef __attribute__((ext_vector_type(8))) _Float16 f16x8;
typedef __attribute__((ext_vector_type(16))) float f32x16;

// sat (128,4,64,16) f32, grd (128,4,64,16) f32
// out (f32): sat 524288 | grd 524288 | distance[g][s] 16384 | orien[s][g] 16384
#define DIST_OFF  1048576
#define ORI_OFF   1064960
#define SATP_STR  72      // f16 elems per satP row (144 B = 36 dwords)

#define MFMA(a,b,c) __builtin_amdgcn_mfma_f32_32x32x16_f16((a),(b),(c),0,0,0)

// ---- prep: grd -> frag-ready grdF[kb][g] HI-ONLY f16x8 (k = w*64 + h*16 + c) ----
// Proven in R6 (absmax 0.0). 64 blocks, 256 threads.
__global__ __launch_bounds__(256) void prep_k(const float* __restrict__ grd,
                                              f16* __restrict__ gHi) {
    const int b = blockIdx.x;
    __shared__ f16 tH[8192];                    // [kb_l 64][g_l 16][e 8]
    const int tid = threadIdx.x;
    const int g0 = (b & 7) * 16;
    const int kq = b >> 3;                      // k-range [kq*512, kq*512+512)
    #pragma unroll
    for (int i = 0; i < 32; ++i) {
        int flat = i * 256 + tid;               // [g_l 16][h 4][j 128], coalesced reads
        int g_l = flat >> 9;
        int r   = flat & 511;
        int h   = r >> 7;
        int j   = r & 127;                      // dw_l = j>>4, c = j&15
        float v = grd[(((g0 + g_l) * 4 + h) * 64 + kq * 8) * 16 + j];
        int k_l = (j >> 4) * 64 + h * 16 + (j & 15);
        tH[(k_l >> 3) * 128 + g_l * 8 + (k_l & 7)] = (f16)v;
    }
    __syncthreads();
    #pragma unroll
    for (int i = 0; i < 4; ++i) {
        int f = i * 256 + tid;                  // frag: kb_l = f>>4, g_l = f&15
        int dst = (kq * 64 + (f >> 4)) * 128 + g0 + (f & 15);
        ((f16x8*)gHi)[dst] = *(const f16x8*)(tH + f * 8);
    }
}

// ---- corr: block=(s, g-quarter32), 8 waves = 8-way K split, wave tile 64j x 32g ----
// HI-ONLY K-loop (1/3 MFMA, 1/2 LDS+L2 of hi/lo) with R9's proven A/B prefetch,
// then R6's PROVEN exact-f32 candidate fixup, reading a transposed padded corrT
// (stride 65) so argmax reads are bank-conflict-free (R6's 64-way-conflict fix).
__global__ __launch_bounds__(512, 4) void corr_k(const float* __restrict__ sat,
                                                 const float* __restrict__ grd,
                                                 const f16* __restrict__ gHi,
                                                 float* __restrict__ out,
                                                 const float4* __restrict__ satIn,
                                                 const float4* __restrict__ grdIn,
                                                 float4* __restrict__ out4,
                                                 int doCopy) {
    __shared__ __align__(16) unsigned char smem[65536];  // satP-hi 18.3KB; red[8][64][32] aliases
    __shared__ float corrT[32 * 65];      // [g 32][j 64] pad->65: conflict-free by-row reads
    __shared__ float wred[8];
    __shared__ float rnormS;
    f16* sH = (f16*)smem;                 // [w' 0..126][hc 0..63], stride 72
    float* red = (float*)smem;            // [kq 8][j 64][g 32] = 16384 f = 64KB

    const int tid = threadIdx.x;
    const int s  = blockIdx.x >> 2;
    const int gq = blockIdx.x & 3;
    const int wave = tid >> 6, lane = tid & 63;
    const int m = lane & 31, half = lane >> 5;

    // ---- hoisted passthrough copy load (consumed at kernel exit) ----
    float4 cpy0;
    int ci = blockIdx.x * 512 + tid;
    if (doCopy) cpy0 = (ci < 131072) ? satIn[ci] : grdIn[ci - 131072];

    // ---- stage satP hi (doubled along w) + ||sat[s]||^2 (round-0 exact ssq order) ----
    const float* satS = sat + s * 4096;
    float ssq = 0.f;
    #pragma unroll
    for (int r = 0; r < 8; ++r) {
        int idx = r * 512 + tid;
        float v = satS[idx];
        int h = idx >> 10, w = (idx >> 4) & 63, c = idx & 15;
        int col = h * 16 + c;
        f16 hv = (f16)v;
        sH[w * SATP_STR + col] = hv;
        if (w < 63) sH[(w + 64) * SATP_STR + col] = hv;
        ssq += v * v;
    }
    #pragma unroll
    for (int off = 32; off > 0; off >>= 1) ssq += __shfl_down(ssq, off, 64);
    if (lane == 0) wred[wave] = ssq;
    __syncthreads();

    // ---- K-loop: kq = wave, 32 k-tiles of 16; A AND B double-buffered, hi-only ----
    const f16* A0h = sH + m * SATP_STR + half * 8;
    const f16x8* BHp = (const f16x8*)gHi;
    const int bBase = half * 128 + gq * 32 + m;      // frag idx = t*256 + bBase

    f32x16 z;
    #pragma unroll
    for (int r = 0; r < 16; ++r) z[r] = 0.f;
    f32x16 h0 = z, h1 = z;

    f16x8 a0[2], a1[2], bh[2];

#define LOADB(p, t) { bh[p] = BHp[(t) * 256 + bBase]; }
#define LOADA(p, t) { int ao = ((t) >> 2) * SATP_STR + ((t) & 3) * 16; \
    a0[p] = *(const f16x8*)(A0h + ao); \
    a1[p] = *(const f16x8*)(A0h + ao + 32 * SATP_STR); }

    const int t0 = wave * 32;
    LOADA(0, t0) LOADB(0, t0)
    #pragma unroll
    for (int tt = 0; tt < 32; ++tt) {
        if (tt < 31) { LOADA((tt + 1) & 1, t0 + tt + 1) LOADB((tt + 1) & 1, t0 + tt + 1) }
        h0 = MFMA(a0[tt & 1], bh[tt & 1], h0);
        h1 = MFMA(a1[tt & 1], bh[tt & 1], h1);
    }

    // ---- 8-way K-partial reduce in LDS (satP dead; red aliases it) ----
    __syncthreads();
    if (tid == 0) {                             // rnorm off the critical path
        float t = 0.f;
        #pragma unroll
        for (int i = 0; i < 8; ++i) t += wred[i];
        rnormS = 1.f / fmaxf(sqrtf(t), 1e-12f);
    }
    float* rw = red + wave * 2048;
    #pragma unroll
    for (int r = 0; r < 16; ++r) {
        int j0 = (r & 3) + 8 * (r >> 2) + 4 * half;      // j within 32-tile
        rw[j0 * 32 + m]        = h0[r];
        rw[(j0 + 32) * 32 + m] = h1[r];
    }
    __syncthreads();
    #pragma unroll
    for (int i = 0; i < 4; ++i) {
        int c = i * 512 + tid;                           // j = c>>5, g = c&31
        float v = red[c]          + red[c + 2048]  + red[c + 4096]  + red[c + 6144]
                + red[c + 8192]   + red[c + 10240] + red[c + 12288] + red[c + 14336];
        corrT[(c & 31) * 65 + (c >> 5)] = v;             // transposed, padded
    }
    __syncthreads();

    // ---- argmax: hi-corr candidates (margin 3.0, R6-proven) + exact-f32 recompute ----
    // wave handles g = wave*4 .. +3; lane = j; corrT row reads are conflict-free.
    const float* gBase = grd + (gq * 32) * 4096;
    #pragma unroll
    for (int i = 0; i < 4; ++i) {
        int g = wave * 4 + i;
        float v = corrT[g * 65 + lane];                  // corr_hi[j=lane][g]
        float mx = v;
        #pragma unroll
        for (int off = 32; off > 0; off >>= 1) mx = fmaxf(mx, __shfl_xor(mx, off, 64));
        unsigned long long mask = __ballot(v >= mx - 3.0f);
        float bestDot = -3.4e38f; int bj = 0;
        while (mask) {
            int j = __ffsll((long long)mask) - 1;        // ascending j
            mask &= mask - 1;
            // exact dot(j,g): lane = w; sum over h,c (R6's exact sequential order)
            int wsat = (lane + j) & 63;
            const float* gp = gBase + g * 4096;
            float acc = 0.f;
            #pragma unroll
            for (int h = 0; h < 4; ++h) {
                const float4* s4 = (const float4*)(satS + h * 1024 + wsat * 16);
                const float4* g4 = (const float4*)(gp  + h * 1024 + lane * 16);
                #pragma unroll
                for (int q = 0; q < 4; ++q) {
                    float4 a = s4[q], b = g4[q];
                    acc += a.x * b.x; acc += a.y * b.y; acc += a.z * b.z; acc += a.w * b.w;
                }
            }
            #pragma unroll
            for (int off = 32; off > 0; off >>= 1) acc += __shfl_xor(acc, off, 64);
            if (acc > bestDot) { bestDot = acc; bj = j; } // strict > keeps first occurrence
        }
        if (lane == 0) {
            float dot = bestDot * rnormS;
            int gg = gq * 32 + g;
            out[DIST_OFF + gg * 128 + s] = 2.f - 2.f * dot;
            out[ORI_OFF + s * 128 + gg]  = (float)bj;
        }
    }

    // ---- hoisted passthrough copy store ----
    if (doCopy) out4[ci] = cpy0;
}

// Fallback passthrough copies (when grdF was staged inside d_out's sat region)
__global__ void copy_k(const float4* __restrict__ a, const float4* __restrict__ b,
                       float4* __restrict__ out) {
    int i = blockIdx.x * 256 + threadIdx.x;
    out[i] = a[i];
    out[131072 + i] = b[i];
}

extern "C" void kernel_launch(void* const* d_in, const int* in_sizes, int n_in,
                              void* d_out, int out_size, void* d_ws, size_t ws_size,
                              hipStream_t stream) {
    const float* sat = (const float*)d_in[0];
    const float* grd = (const float*)d_in[1];
    float* out = (float*)d_out;

    // ws poison fill is unconditional (proven R2), so using d_ws costs nothing.
    const bool useWs = (ws_size >= (size_t)1024 * 1024 * 2);
    f16* gHi;
    if (useWs) {
        gHi = (f16*)d_ws;
    } else {
        gHi = (f16*)out;                 // 1 MB inside out's sat region
    }

    prep_k<<<64, 256, 0, stream>>>(grd, gHi);
    corr_k<<<512, 512, 0, stream>>>(sat, grd, gHi, out,
                                    (const float4*)sat, (const float4*)grd, (float4*)out,
                                    useWs ? 1 : 0);
    if (!useWs)
        copy_k<<<512, 256, 0, stream>>>((const float4*)sat, (const float4*)grd, (float4*)out);
}

// Round 11
// 82.075 us; speedup vs baseline: 1.2815x; 1.2815x over previous
//
#include <hip/hip_runtime.h>
#include <math.h>

typedef _Float16 f16;
typedef __attribute__((ext_vector_type(8))) _Float16 f16x8;
typedef __attribute__((ext_vector_type(16))) float f32x16;

// sat (128,4,64,16) f32, grd (128,4,64,16) f32
// out (f32): sat 524288 | grd 524288 | distance[g][s] 16384 | orien[s][g] 16384
#define DIST_OFF  1048576
#define ORI_OFF   1064960
#define SATP_STR  72      // f16 elems per satP row (144 B = 36 dwords)

#define MFMA(a,b,c) __builtin_amdgcn_mfma_f32_32x32x16_f16((a),(b),(c),0,0,0)

// ---- prep: grd -> frag-ready grdF[kb][g] HI-ONLY f16x8 (k = w*64 + h*16 + c) ----
// Proven R6/R10 (absmax 0.0). 64 blocks, 256 threads.
__global__ __launch_bounds__(256) void prep_k(const float* __restrict__ grd,
                                              f16* __restrict__ gHi) {
    const int b = blockIdx.x;
    __shared__ f16 tH[8192];                    // [kb_l 64][g_l 16][e 8]
    const int tid = threadIdx.x;
    const int g0 = (b & 7) * 16;
    const int kq = b >> 3;                      // k-range [kq*512, kq*512+512)
    #pragma unroll
    for (int i = 0; i < 32; ++i) {
        int flat = i * 256 + tid;               // [g_l 16][h 4][j 128], coalesced reads
        int g_l = flat >> 9;
        int r   = flat & 511;
        int h   = r >> 7;
        int j   = r & 127;                      // dw_l = j>>4, c = j&15
        float v = grd[(((g0 + g_l) * 4 + h) * 64 + kq * 8) * 16 + j];
        int k_l = (j >> 4) * 64 + h * 16 + (j & 15);
        tH[(k_l >> 3) * 128 + g_l * 8 + (k_l & 7)] = (f16)v;
    }
    __syncthreads();
    #pragma unroll
    for (int i = 0; i < 4; ++i) {
        int f = i * 256 + tid;                  // frag: kb_l = f>>4, g_l = f&15
        int dst = (kq * 64 + (f >> 4)) * 128 + g0 + (f & 15);
        ((f16x8*)gHi)[dst] = *(const f16x8*)(tH + f * 8);
    }
}

// ---- corr: block=(s, g-quarter32), 8 waves = 8-way K split, wave tile 64j x 32g ----
// HI-ONLY K-loop; argmax via hi-corr with margin 2.0:
//   single candidate  -> certified argmax, hi-dot distance (err ~0.002 << 1.26 thr)
//   multi candidates  -> R6-PROVEN exact-f32 recompute (absmax 0.0 twice)
__global__ __launch_bounds__(512, 4) void corr_k(const float* __restrict__ sat,
                                                 const float* __restrict__ grd,
                                                 const f16* __restrict__ gHi,
                                                 float* __restrict__ out,
                                                 const float4* __restrict__ satIn,
                                                 const float4* __restrict__ grdIn,
                                                 float4* __restrict__ out4,
                                                 int doCopy) {
    __shared__ __align__(16) unsigned char smem[65536];  // satP-hi 18.3KB; red[8][64][32] aliases
    __shared__ float corrT[32 * 65];      // [g 32][j 64] pad->65: conflict-free by-row reads
    __shared__ float wred[8];
    __shared__ float rnormS;
    f16* sH = (f16*)smem;                 // [w' 0..126][hc 0..63], stride 72
    float* red = (float*)smem;            // [kq 8][j 64][g 32] = 16384 f = 64KB

    const int tid = threadIdx.x;
    const int s  = blockIdx.x >> 2;
    const int gq = blockIdx.x & 3;
    const int wave = tid >> 6, lane = tid & 63;
    const int m = lane & 31, half = lane >> 5;

    // ---- hoisted passthrough copy load (consumed at kernel exit) ----
    float4 cpy0;
    int ci = blockIdx.x * 512 + tid;
    if (doCopy) cpy0 = (ci < 131072) ? satIn[ci] : grdIn[ci - 131072];

    // ---- stage satP hi (doubled along w) + ||sat[s]||^2 (round-0 exact ssq order) ----
    const float* satS = sat + s * 4096;
    float ssq = 0.f;
    #pragma unroll
    for (int r = 0; r < 8; ++r) {
        int idx = r * 512 + tid;
        float v = satS[idx];
        int h = idx >> 10, w = (idx >> 4) & 63, c = idx & 15;
        int col = h * 16 + c;
        f16 hv = (f16)v;
        sH[w * SATP_STR + col] = hv;
        if (w < 63) sH[(w + 64) * SATP_STR + col] = hv;
        ssq += v * v;
    }
    #pragma unroll
    for (int off = 32; off > 0; off >>= 1) ssq += __shfl_down(ssq, off, 64);
    if (lane == 0) wred[wave] = ssq;
    __syncthreads();

    // ---- K-loop: kq = wave, 32 k-tiles of 16; A AND B double-buffered, hi-only ----
    const f16* A0h = sH + m * SATP_STR + half * 8;
    const f16x8* BHp = (const f16x8*)gHi;
    const int bBase = half * 128 + gq * 32 + m;      // frag idx = t*256 + bBase

    f32x16 z;
    #pragma unroll
    for (int r = 0; r < 16; ++r) z[r] = 0.f;
    f32x16 h0 = z, h1 = z;

    f16x8 a0[2], a1[2], bh[2];

#define LOADB(p, t) { bh[p] = BHp[(t) * 256 + bBase]; }
#define LOADA(p, t) { int ao = ((t) >> 2) * SATP_STR + ((t) & 3) * 16; \
    a0[p] = *(const f16x8*)(A0h + ao); \
    a1[p] = *(const f16x8*)(A0h + ao + 32 * SATP_STR); }

    const int t0 = wave * 32;
    LOADA(0, t0) LOADB(0, t0)
    #pragma unroll
    for (int tt = 0; tt < 32; ++tt) {
        if (tt < 31) { LOADA((tt + 1) & 1, t0 + tt + 1) LOADB((tt + 1) & 1, t0 + tt + 1) }
        h0 = MFMA(a0[tt & 1], bh[tt & 1], h0);
        h1 = MFMA(a1[tt & 1], bh[tt & 1], h1);
    }

    // ---- 8-way K-partial reduce in LDS (satP dead; red aliases it) ----
    __syncthreads();
    if (tid == 0) {                             // rnorm off the critical path
        float t = 0.f;
        #pragma unroll
        for (int i = 0; i < 8; ++i) t += wred[i];
        rnormS = 1.f / fmaxf(sqrtf(t), 1e-12f);
    }
    float* rw = red + wave * 2048;
    #pragma unroll
    for (int r = 0; r < 16; ++r) {
        int j0 = (r & 3) + 8 * (r >> 2) + 4 * half;      // j within 32-tile
        rw[j0 * 32 + m]        = h0[r];
        rw[(j0 + 32) * 32 + m] = h1[r];
    }
    __syncthreads();
    #pragma unroll
    for (int i = 0; i < 4; ++i) {
        int c = i * 512 + tid;                           // j = c>>5, g = c&31
        float v = red[c]          + red[c + 2048]  + red[c + 4096]  + red[c + 6144]
                + red[c + 8192]   + red[c + 10240] + red[c + 12288] + red[c + 14336];
        corrT[(c & 31) * 65 + (c >> 5)] = v;             // transposed, padded
    }
    __syncthreads();

    // ---- argmax: hi-corr candidates (margin 2.0); fast path when unique ----
    const float* gBase = grd + (gq * 32) * 4096;
    #pragma unroll
    for (int i = 0; i < 4; ++i) {
        int g = wave * 4 + i;
        float v = corrT[g * 65 + lane];                  // corr_hi[j=lane][g]
        float mx = v;
        #pragma unroll
        for (int off = 32; off > 0; off >>= 1) mx = fmaxf(mx, __shfl_xor(mx, off, 64));
        unsigned long long mask = __ballot(v >= mx - 2.0f);
        float bestDot; int bj;
        if (__popcll(mask) == 1) {
            // unique candidate: certified argmax; hi-dot distance (err ~0.002 << 1.26)
            bj = __ffsll((long long)mask) - 1;
            bestDot = __shfl(v, bj, 64);
        } else {
            // R6-proven exact-f32 recompute over candidates (ascending j, strict >)
            bestDot = -3.4e38f; bj = 0;
            while (mask) {
                int j = __ffsll((long long)mask) - 1;
                mask &= mask - 1;
                int wsat = (lane + j) & 63;
                const float* gp = gBase + g * 4096;
                float acc = 0.f;
                #pragma unroll
                for (int h = 0; h < 4; ++h) {
                    const float4* s4 = (const float4*)(satS + h * 1024 + wsat * 16);
                    const float4* g4 = (const float4*)(gp  + h * 1024 + lane * 16);
                    #pragma unroll
                    for (int q = 0; q < 4; ++q) {
                        float4 a = s4[q], b = g4[q];
                        acc += a.x * b.x; acc += a.y * b.y; acc += a.z * b.z; acc += a.w * b.w;
                    }
                }
                #pragma unroll
                for (int off = 32; off > 0; off >>= 1) acc += __shfl_xor(acc, off, 64);
                if (acc > bestDot) { bestDot = acc; bj = j; }
            }
        }
        if (lane == 0) {
            float dot = bestDot * rnormS;
            int gg = gq * 32 + g;
            out[DIST_OFF + gg * 128 + s] = 2.f - 2.f * dot;
            out[ORI_OFF + s * 128 + gg]  = (float)bj;
        }
    }

    // ---- hoisted passthrough copy store ----
    if (doCopy) out4[ci] = cpy0;
}

// Fallback passthrough copies (when grdF was staged inside d_out's sat region)
__global__ void copy_k(const float4* __restrict__ a, const float4* __restrict__ b,
                       float4* __restrict__ out) {
    int i = blockIdx.x * 256 + threadIdx.x;
    out[i] = a[i];
    out[131072 + i] = b[i];
}

extern "C" void kernel_launch(void* const* d_in, const int* in_sizes, int n_in,
                              void* d_out, int out_size, void* d_ws, size_t ws_size,
                              hipStream_t stream) {
    const float* sat = (const float*)d_in[0];
    const float* grd = (const float*)d_in[1];
    float* out = (float*)d_out;

    // ws poison fill is unconditional (proven R2), so using d_ws costs nothing.
    const bool useWs = (ws_size >= (size_t)1024 * 1024 * 2);
    f16* gHi;
    if (useWs) {
        gHi = (f16*)d_ws;
    } else {
        gHi = (f16*)out;                 // 1 MB inside out's sat region
    }

    prep_k<<<64, 256, 0, stream>>>(grd, gHi);
    corr_k<<<512, 512, 0, stream>>>(sat, grd, gHi, out,
                                    (const float4*)sat, (const float4*)grd, (float4*)out,
                                    useWs ? 1 : 0);
    if (!useWs)
        copy_k<<<512, 256, 0, stream>>>((const float4*)sat, (const float4*)grd, (float4*)out);
}